// Round 3
// baseline (139.510 us; speedup 1.0000x reference)
//
#include <hip/hip_runtime.h>
#include <hip/hip_bf16.h>

// Sinusoidal positional encoding, broadcast to (n, 1, length).
// length = 8192, n = 4096 (fixed). Output float32 (134.2 MB).
//
// R2 post-mortem: single fused kernel ran at 138 us (~1 TB/s) while the
// harness's own fill kernel sustains 6.6 TB/s. The per-thread accurate
// libm (expf/sinf/cosf, OCML range reduction) redundantly recomputed
// 4096x per column was the serializing cost.
//
// Structure now:
//   Kernel 1 (8 blocks): compute the 8192-float row ONCE with accurate
//     libm, write it to row 0 of d_out. (No d_ws use -> no ws_size risk.)
//   Kernel 2 (2048 blocks): pure broadcast. One float4 load from row 0
//     (L2/L3-resident, 32 KB unique) + 16 coalesced float4 stores.
//     Should match the fill kernel's ~6.6 TB/s -> ~21 us.

#define LENGTH 8192
#define NROWS  4096

#define THREADS        256
#define COLS_PER_THR   4
#define COLS_PER_BLK   (THREADS * COLS_PER_THR)   // 1024
#define COL_BLKS       (LENGTH / COLS_PER_BLK)    // 8
#define ROW_BLKS       256
#define ROWS_PER_BLK   (NROWS / ROW_BLKS)         // 16

// ---- Kernel 1: compute the encoding row into out[0, 0, :] ----
__global__ __launch_bounds__(THREADS)
void sinusoid_row_kernel(const float* __restrict__ pos_p,
                         float* __restrict__ out) {
    const float position = pos_p[0];
    const int t = blockIdx.x * THREADS + threadIdx.x;   // 0..2047
    const int col0 = t * COLS_PER_THR;

    // 1000^(-i/length) = exp(i * (-ln(1000)/length))
    const float kNegLn1000OverL = -6.90775527898213705f / (float)LENGTH;

    float4 v;
    const float a0 = position * expf((float)(col0)     * kNegLn1000OverL);
    const float a1 = position * expf((float)(col0 + 2) * kNegLn1000OverL);
    v.x = sinf(a0);
    v.y = cosf(a0);
    v.z = sinf(a1);
    v.w = cosf(a1);

    *reinterpret_cast<float4*>(out + col0) = v;
}

// ---- Kernel 2: broadcast row 0 to all NROWS rows ----
__global__ __launch_bounds__(THREADS)
void sinusoid_bcast_kernel(float* __restrict__ out) {
    const int colblk = blockIdx.x & (COL_BLKS - 1);
    const int rowblk = blockIdx.x >> 3;            // / COL_BLKS
    const int col0   = colblk * COLS_PER_BLK + threadIdx.x * COLS_PER_THR;

    const float4 v = *reinterpret_cast<const float4*>(out + col0);

    const size_t base = (size_t)rowblk * ROWS_PER_BLK * LENGTH + (size_t)col0;
#pragma unroll
    for (int r = 0; r < ROWS_PER_BLK; ++r) {
        // rowblk 0 rewrites row 0 with identical bits -- harmless.
        *reinterpret_cast<float4*>(out + base + (size_t)r * LENGTH) = v;
    }
}

extern "C" void kernel_launch(void* const* d_in, const int* in_sizes, int n_in,
                              void* d_out, int out_size, void* d_ws, size_t ws_size,
                              hipStream_t stream) {
    // d_in[0] = length (int) -- fixed 8192
    // d_in[1] = n      (int) -- fixed 4096
    // d_in[2] = position (float, 1 elem)
    const float* pos = (const float*)d_in[2];
    float* out = (float*)d_out;

    sinusoid_row_kernel<<<dim3(LENGTH / COLS_PER_THR / THREADS), dim3(THREADS), 0, stream>>>(pos, out);
    sinusoid_bcast_kernel<<<dim3(COL_BLKS * ROW_BLKS), dim3(THREADS), 0, stream>>>(out);
}